// Round 1
// baseline (37960.620 us; speedup 1.0000x reference)
//
#include <hip/hip_runtime.h>

#define BB 32
#define TT 512
#define HH 1024
#define BH (BB*HH)

__device__ __forceinline__ float wave_sum(float v) {
  v += __shfl_xor(v, 32, 64);
  v += __shfl_xor(v, 16, 64);
  v += __shfl_xor(v,  8, 64);
  v += __shfl_xor(v,  4, 64);
  v += __shfl_xor(v,  2, 64);
  v += __shfl_xor(v,  1, 64);
  return v;
}

__device__ __forceinline__ float sigmoidf_(float x) { return 1.0f / (1.0f + __expf(-x)); }

// One time step of both directions' stacked-LSTM layer.
// Each wave: one hidden unit j, 16 batch rows, all 4 gate rows (i,f,g,o).
// K (2048 = x 1024 + h 1024) split across the 64 lanes, float4 loads.
__global__ __launch_bounds__(256)
void lstm_step(const float* __restrict__ xf, const float* __restrict__ xb,
               const float* __restrict__ WihF, const float* __restrict__ WhhF, const float* __restrict__ biasF,
               const float* __restrict__ WihB, const float* __restrict__ WhhB, const float* __restrict__ biasB,
               const float* __restrict__ hfp, float* __restrict__ hfn, float* __restrict__ cf,
               const float* __restrict__ hbp, float* __restrict__ hbn, float* __restrict__ cb,
               float* __restrict__ outF, float* __restrict__ outB,
               int tf, int tb)
{
  const int dir = blockIdx.y;
  const float* xseq = dir ? xb   : xf;
  const float* Wih  = dir ? WihB : WihF;
  const float* Whh  = dir ? WhhB : WhhF;
  const float* bias = dir ? biasB: biasF;
  const float* hp   = dir ? hbp  : hfp;
  float* hn         = dir ? hbn  : hfn;
  float* cs         = dir ? cb   : cf;
  float* oseq       = dir ? outB : outF;
  const int t       = dir ? tb   : tf;

  const int wave = threadIdx.x >> 6;
  const int lane = threadIdx.x & 63;
  const int j  = blockIdx.x * 2 + (wave >> 1);   // hidden unit
  const int b0 = (wave & 1) * 16;                // batch half

  const float4* Wi4 = (const float4*)Wih;
  const float4* Wh4 = (const float4*)Whh;
  const float4* x4  = (const float4*)xseq;
  const float4* h4  = (const float4*)hp;

  // gate rows (float4 units): i=j, f=H+j, g=2H+j, o=3H+j ; row length H -> 256 float4
  const int r0 = j*256, r1 = (HH + j)*256, r2 = (2*HH + j)*256, r3 = (3*HH + j)*256;

  float a0[16], a1[16], a2[16], a3[16];
  #pragma unroll
  for (int q = 0; q < 16; ++q) { a0[q]=0.f; a1[q]=0.f; a2[q]=0.f; a3[q]=0.f; }

  // phase 1: x_t @ Wih^T
  #pragma unroll
  for (int c = 0; c < 4; ++c) {
    const int kv = c*64 + lane;
    const float4 w0 = Wi4[r0+kv], w1 = Wi4[r1+kv], w2 = Wi4[r2+kv], w3 = Wi4[r3+kv];
    #pragma unroll
    for (int q = 0; q < 16; ++q) {
      const float4 xv = x4[((b0+q)*TT + t)*256 + kv];
      a0[q] = fmaf(w0.x,xv.x, fmaf(w0.y,xv.y, fmaf(w0.z,xv.z, fmaf(w0.w,xv.w, a0[q]))));
      a1[q] = fmaf(w1.x,xv.x, fmaf(w1.y,xv.y, fmaf(w1.z,xv.z, fmaf(w1.w,xv.w, a1[q]))));
      a2[q] = fmaf(w2.x,xv.x, fmaf(w2.y,xv.y, fmaf(w2.z,xv.z, fmaf(w2.w,xv.w, a2[q]))));
      a3[q] = fmaf(w3.x,xv.x, fmaf(w3.y,xv.y, fmaf(w3.z,xv.z, fmaf(w3.w,xv.w, a3[q]))));
    }
  }
  // phase 2: h_{t-1} @ Whh^T
  #pragma unroll
  for (int c = 0; c < 4; ++c) {
    const int kv = c*64 + lane;
    const float4 w0 = Wh4[r0+kv], w1 = Wh4[r1+kv], w2 = Wh4[r2+kv], w3 = Wh4[r3+kv];
    #pragma unroll
    for (int q = 0; q < 16; ++q) {
      const float4 hv = h4[(b0+q)*256 + kv];
      a0[q] = fmaf(w0.x,hv.x, fmaf(w0.y,hv.y, fmaf(w0.z,hv.z, fmaf(w0.w,hv.w, a0[q]))));
      a1[q] = fmaf(w1.x,hv.x, fmaf(w1.y,hv.y, fmaf(w1.z,hv.z, fmaf(w1.w,hv.w, a1[q]))));
      a2[q] = fmaf(w2.x,hv.x, fmaf(w2.y,hv.y, fmaf(w2.z,hv.z, fmaf(w2.w,hv.w, a2[q]))));
      a3[q] = fmaf(w3.x,hv.x, fmaf(w3.y,hv.y, fmaf(w3.z,hv.z, fmaf(w3.w,hv.w, a3[q]))));
    }
  }

  // reduce across 64 lanes; lane q keeps batch row b0+q's four gate pre-activations
  float gi = 0.f, gf = 0.f, gg = 0.f, go = 0.f;
  #pragma unroll
  for (int q = 0; q < 16; ++q) {
    const float s0 = wave_sum(a0[q]);
    const float s1 = wave_sum(a1[q]);
    const float s2 = wave_sum(a2[q]);
    const float s3 = wave_sum(a3[q]);
    if (lane == q) { gi = s0; gf = s1; gg = s2; go = s3; }
  }

  if (lane < 16) {
    const int b = b0 + lane;
    gi += bias[j];
    gf += bias[HH + j];
    gg += bias[2*HH + j];
    go += bias[3*HH + j];
    const float ig = sigmoidf_(gi);
    const float fg = sigmoidf_(gf);
    const float gv = tanhf(gg);
    const float og = sigmoidf_(go);
    const float cold = cs[b*HH + j];
    const float cn = fg*cold + ig*gv;
    const float hv = og * tanhf(cn);
    cs[b*HH + j] = cn;
    hn[b*HH + j] = hv;
    oseq[((size_t)b*TT + t)*HH + j] = hv;
  }
}

// out[b,t,0:H] = fwd[b,t,:], out[b,t,H:2H] = bwd[b,t,:]
__global__ __launch_bounds__(256)
void concat_kernel(const float4* __restrict__ fwd, const float4* __restrict__ bwd,
                   float4* __restrict__ out) {
  const int i = blockIdx.x * blockDim.x + threadIdx.x;   // over B*T*H/4
  if (i >= BB*TT*HH/4) return;
  const int row = i >> 8;     // b*T + t   (H/4 = 256)
  const int col = i & 255;
  out[(size_t)row*512 + col]       = fwd[i];
  out[(size_t)row*512 + 256 + col] = bwd[i];
}

extern "C" void kernel_launch(void* const* d_in, const int* in_sizes, int n_in,
                              void* d_out, int out_size, void* d_ws, size_t ws_size,
                              hipStream_t stream) {
  const float* x    = (const float*)d_in[0];
  const float* WihF = (const float*)d_in[1];
  const float* WhhF = (const float*)d_in[2];
  const float* bF   = (const float*)d_in[3];
  const float* WihB = (const float*)d_in[4];
  const float* WhhB = (const float*)d_in[5];
  const float* bB   = (const float*)d_in[6];

  float* out = (float*)d_out;
  float* fwd = out + (size_t)BB*TT*2*HH;           // output 1 region
  float* bwd = fwd + (size_t)BB*TT*HH;             // output 2 region
  // layer-0 output sequences staged in the (later overwritten) out region:
  float* sf0 = out;
  float* sb0 = out + (size_t)BB*TT*HH;

  float* ws  = (float*)d_ws;
  float* hf0 = ws;            float* hf1 = ws + BH;
  float* cfb = ws + 2*BH;
  float* hb0 = ws + 3*BH;     float* hb1 = ws + 4*BH;
  float* cbb = ws + 5*BH;

  const size_t WL = (size_t)4*HH*HH;   // per-layer weight block
  const size_t BL = (size_t)4*HH;      // per-layer bias block

  dim3 grid(HH/2, 2), block(256);

  // ---- layer 0 (input: x for both directions) ----
  hipMemsetAsync(d_ws, 0, (size_t)6*BH*sizeof(float), stream);
  for (int s = 0; s < TT; ++s) {
    const float* hfp = (s & 1) ? hf1 : hf0;  float* hfn = (s & 1) ? hf0 : hf1;
    const float* hbp = (s & 1) ? hb1 : hb0;  float* hbn = (s & 1) ? hb0 : hb1;
    lstm_step<<<grid, block, 0, stream>>>(x, x,
        WihF, WhhF, bF, WihB, WhhB, bB,
        hfp, hfn, cfb, hbp, hbn, cbb,
        sf0, sb0, s, TT-1-s);
  }

  // ---- layer 1 (input: layer-0 output sequences) ----
  hipMemsetAsync(d_ws, 0, (size_t)6*BH*sizeof(float), stream);
  for (int s = 0; s < TT; ++s) {
    const float* hfp = (s & 1) ? hf1 : hf0;  float* hfn = (s & 1) ? hf0 : hf1;
    const float* hbp = (s & 1) ? hb1 : hb0;  float* hbn = (s & 1) ? hb0 : hb1;
    lstm_step<<<grid, block, 0, stream>>>(sf0, sb0,
        WihF + WL, WhhF + WL, bF + BL, WihB + WL, WhhB + WL, bB + BL,
        hfp, hfn, cfb, hbp, hbn, cbb,
        fwd, bwd, s, TT-1-s);
  }

  // ---- concat fwd/bwd into out (overwrites the scratch region last) ----
  concat_kernel<<<(BB*TT*HH/4 + 255)/256, 256, 0, stream>>>(
      (const float4*)fwd, (const float4*)bwd, (float4*)out);
}